// Round 5
// baseline (465.169 us; speedup 1.0000x reference)
//
#include <hip/hip_runtime.h>
#include <hip/hip_cooperative_groups.h>
#include <math.h>

namespace cg = cooperative_groups;

#define NPTS 50000
#define NG   128
#define DD   32
#define FF   64
#define AA   8
#define HINC 1120   // DD + FF + 2*FF*AA
#define EPSV 1e-5f
#define CH   64
#define NT   512
#define SMAX 10     // fallback slots per graph

__device__ __forceinline__ float tanh_fast(float x) {
    float e = __expf(-2.f * fabsf(x));
    float r = __fdividef(1.f - e, 1.f + e);
    return copysignf(r, x);
}

struct KP {
    const float* x; const int* batch;
    const float *Wi, *bi, *lni_w, *lni_b;
    const float *W_in, *b_in, *W_sc, *b_sc, *W_out, *b_out, *gln_w, *gln_b;
    const float *Wp, *bp, *lnp_w, *lnp_b, *Wpo, *bpo;
    float* out;
    float *h, *tbuf, *aggW, *stats, *Weff, *beff, *psum, *pmax;
    int* offs;
};

// ==================================================================
// Cooperative mega-kernel. All phases grid-stride over jobs so any
// grid size >= 16 blocks is correct. 2 grid.sync per layer.
// LDS union: phase A: sWin[2048]|sScT[512]|hs 64x36[2304]|sxp 64x64[4096]|sattn 64x8[512] = 9472 fl
//            phase BC: agg[1024]|red[512]|aggWs[32]|sW 32x36[1152]|hs 64x36[2304]
// ==================================================================
__global__ __launch_bounds__(NT, 2) void mega(KP p) {
    cg::grid_group grid = cg::this_grid();
    __shared__ float lds[9472];          // 37888 B
    __shared__ float rs1[8], rs2[8];
    const int t = threadIdx.x;
    const int bid = blockIdx.x;
    const int nb = gridDim.x;

    // ================= setup: embed + offs/stats + fold =================
    for (int n = bid*NT + t; n < NPTS; n += nb*NT) {
        float x0 = p.x[n*3], x1 = p.x[n*3+1], x2 = p.x[n*3+2];
        float v[DD]; float mm = 0.f;
        #pragma unroll
        for (int d = 0; d < DD; d++) {
            float tv = x0*p.Wi[d] + x1*p.Wi[DD+d] + x2*p.Wi[2*DD+d] + p.bi[d];
            v[d] = tv; mm += tv;
        }
        mm *= (1.f/DD);
        float var = 0.f;
        #pragma unroll
        for (int d = 0; d < DD; d++) { float c = v[d]-mm; var += c*c; }
        var *= (1.f/DD);
        float inv = 1.f/sqrtf(var + EPSV);
        #pragma unroll
        for (int d = 0; d < DD; d++)
            p.h[(size_t)n*DD + d] = tanh_fast((v[d]-mm)*inv*p.lni_w[d] + p.lni_b[d]);
    }
    if (bid == 0) {
        if (t <= NG) {
            int lo = 0, hi = NPTS;
            while (lo < hi) { int mid = (lo+hi)>>1; if (p.batch[mid] < t) lo = mid+1; else hi = mid; }
            p.offs[t] = lo;
        }
        if (t < 32) p.stats[t] = 0.f;
    }
    if (bid >= 1 && bid <= 3) {
        int j = bid - 1;
        const float* W0 = p.W_out + (size_t)j*HINC*DD;   // rows 0..31
        const float* W1 = W0 + DD*DD;                    // rows 32..95
        const float* Wn = p.W_in + (size_t)j*DD*FF;
        for (int e = t; e < DD*DD; e += NT) {
            int i = e >> 5, d = e & 31;
            float s = W0[e];
            for (int f = 0; f < FF; f++) s += Wn[i*FF+f] * W1[f*DD+d];
            p.Weff[j*DD*DD + e] = s;
        }
        if (t < DD) {
            float s = p.b_out[j*DD + t];
            for (int f = 0; f < FF; f++) s += p.b_in[j*FF+f] * W1[f*DD+t];
            p.beff[j*DD + t] = s;
        }
    }
    grid.sync();

    // ================= 9 bipartite layers =================
    for (int L = 0; L < 9; ++L) {
        const int j = L % 3;
        const float* inb = L ? p.tbuf : p.h;
        float gm = 0.f, ginv = 1.f;
        const float* pgw = nullptr; const float* pgb = nullptr;
        if (L) {
            const float* st = p.stats + 2*(L-1);
            const float invM = 1.f/((float)NPTS*DD);
            gm = st[0]*invM;
            float var = st[1]*invM - gm*gm;
            ginv = 1.f/(sqrtf(fmaxf(var, 0.f)) + EPSV);
            int pj = (L+2) % 3;
            pgw = p.gln_w + pj*DD; pgb = p.gln_b + pj*DD;
        }

        // ---------- phase A: gln -> xp -> attn -> partial (sum,max) per graph-half ----------
        {
            float* sWin = lds;                                // 2048
            float* sScT = lds + 2048;                         // 512
            float (*hs)[36]  = (float(*)[36])(lds + 2560);    // 2304
            float (*sxp)[64] = (float(*)[64])(lds + 4864);    // 4096
            float (*sattn)[8]= (float(*)[8]) (lds + 8960);    // 512
            const float* Win = p.W_in + (size_t)j*DD*FF;
            const float* Wsc = p.W_sc + (size_t)j*FF*AA;
            const float* bin = p.b_in + j*FF;
            const float* bsc = p.b_sc + j*AA;
            for (int k = t; k < DD*FF; k += NT) sWin[k] = Win[k];
            { int a = t >> 6, f = t & 63; sScT[t] = Wsc[f*AA + a]; }
            const int pt = t >> 3, fo = (t & 7)*8, al = t & 7;
            const int ca = t >> 6, cf = t & 63;
            const float bscv = bsc[al];
            const float4 bi0 = *(const float4*)&bin[fo];
            const float4 bi1 = *(const float4*)&bin[fo+4];
            for (int job = bid; job < NG*2; job += nb) {
                int g = job >> 1, half = job & 1;
                int gs = p.offs[g], cnt = p.offs[g+1] - gs;
                int lo = gs + ((cnt*half) >> 1);
                int hi = gs + ((cnt*(half+1)) >> 1);
                float csum = 0.f, cmax = -INFINITY;
                for (int base = lo; base < hi; base += CH) {
                    int np = min(CH, hi - base);
                    __syncthreads();
                    { // load + gln
                        int pp = t >> 3, d4 = (t & 7)*4;
                        if (pp < np) {
                            int n = base + pp;
                            float4 v = *(const float4*)&inb[(size_t)n*DD + d4];
                            float4 w4 = make_float4(1,1,1,1), b4 = make_float4(0,0,0,0);
                            if (pgw) { w4 = *(const float4*)&pgw[d4]; b4 = *(const float4*)&pgb[d4]; }
                            hs[pp][d4+0] = (v.x-gm)*ginv*w4.x + b4.x;
                            hs[pp][d4+1] = (v.y-gm)*ginv*w4.y + b4.y;
                            hs[pp][d4+2] = (v.z-gm)*ginv*w4.z + b4.z;
                            hs[pp][d4+3] = (v.w-gm)*ginv*w4.w + b4.w;
                        }
                    }
                    __syncthreads();
                    if (pt < np) {  // xp + attn
                        float xr[8] = {bi0.x,bi0.y,bi0.z,bi0.w,bi1.x,bi1.y,bi1.z,bi1.w};
                        #pragma unroll
                        for (int k = 0; k < DD; k++) {
                            float hv = hs[pt][k];
                            float4 wa = *(const float4*)&sWin[k*FF + fo];
                            float4 wb = *(const float4*)&sWin[k*FF + fo + 4];
                            xr[0] += hv*wa.x; xr[1] += hv*wa.y; xr[2] += hv*wa.z; xr[3] += hv*wa.w;
                            xr[4] += hv*wb.x; xr[5] += hv*wb.y; xr[6] += hv*wb.z; xr[7] += hv*wb.w;
                        }
                        float pa[8];
                        #pragma unroll
                        for (int a = 0; a < 8; a++) {
                            float4 wa = *(const float4*)&sScT[a*FF + fo];
                            float4 wb = *(const float4*)&sScT[a*FF + fo + 4];
                            pa[a] = xr[0]*wa.x + xr[1]*wa.y + xr[2]*wa.z + xr[3]*wa.w
                                  + xr[4]*wb.x + xr[5]*wb.y + xr[6]*wb.z + xr[7]*wb.w;
                        }
                        #pragma unroll
                        for (int msk = 1; msk < 8; msk <<= 1) {
                            #pragma unroll
                            for (int a = 0; a < 8; a++) pa[a] += __shfl_xor(pa[a], msk);
                        }
                        sattn[pt][al] = __expf(-fabsf(pa[al] + bscv));
                        *(float4*)&sxp[pt][fo]   = make_float4(xr[0],xr[1],xr[2],xr[3]);
                        *(float4*)&sxp[pt][fo+4] = make_float4(xr[4],xr[5],xr[6],xr[7]);
                    }
                    __syncthreads();
                    for (int pp = 0; pp < np; pp++) {
                        float w = sattn[pp][ca] * sxp[pp][cf];
                        csum += w; cmax = fmaxf(cmax, w);
                    }
                }
                p.psum[(size_t)job*NT + t] = csum;
                p.pmax[(size_t)job*NT + t] = cmax;
            }
        }
        grid.sync();

        // ---------- phase B(+C): reduce -> agg -> aggW (LDS) -> out + stats ----------
        {
            float* agg = lds;                                 // 1024
            float (*red)[DD] = (float(*)[DD])(lds + 1024);    // 512
            float* aggWs = lds + 1536;                        // 32
            float (*sW)[36] = (float(*)[36])(lds + 1568);     // 1152
            float (*hs)[36] = (float(*)[36])(lds + 2720);     // 2304
            for (int k = t; k < DD*DD; k += NT) sW[k>>5][k&31] = p.Weff[(size_t)j*DD*DD + k];
            const float* Wagg = p.W_out + (size_t)j*HINC*DD + 96*DD;
            float s1 = 0.f, s2 = 0.f;
            for (int job = bid; job < NG*2; job += nb) {
                int g = job >> 1, half = job & 1;
                int gs = p.offs[g], cnt = p.offs[g+1] - gs;
                int lo = gs + ((cnt*half) >> 1);
                int hi = gs + ((cnt*(half+1)) >> 1);
                __syncthreads();
                // B (redundant per half): combine both halves' partials
                {
                    size_t pb = (size_t)(g*2)*NT + t;
                    float sum = p.psum[pb] + p.psum[pb + NT];
                    float mx  = fmaxf(p.pmax[pb], p.pmax[pb + NT]);
                    float mean = sum / fmaxf((float)cnt, 1.f);
                    if (cnt <= 0) { mean = 0.f; mx = 0.f; }
                    int a = t >> 6, f = t & 63;
                    agg[a*2*FF + f]      = mean;
                    agg[a*2*FF + FF + f] = mx;
                }
                __syncthreads();
                {
                    int d = t & 31, grp = t >> 5;
                    float acc = 0.f;
                    #pragma unroll
                    for (int k2 = 0; k2 < 64; k2++) {
                        int k = grp*64 + k2;
                        acc += agg[k] * Wagg[k*DD + d];
                    }
                    red[grp][d] = acc;
                }
                __syncthreads();
                if (t < DD) {
                    float r = 0.f;
                    #pragma unroll
                    for (int q = 0; q < 16; q++) r += red[q][t];
                    aggWs[t] = r + p.beff[j*DD + t];
                }
                // C on own half  (aggWs visible after the two syncs inside tile loop)
                for (int base = lo; base < hi; base += CH) {
                    int np = min(CH, hi - base);
                    __syncthreads();
                    {
                        int pp = t >> 3, d4 = (t & 7)*4;
                        if (pp < np) {
                            int n = base + pp;
                            float4 v = *(const float4*)&inb[(size_t)n*DD + d4];
                            float4 w4 = make_float4(1,1,1,1), b4 = make_float4(0,0,0,0);
                            if (pgw) { w4 = *(const float4*)&pgw[d4]; b4 = *(const float4*)&pgb[d4]; }
                            hs[pp][d4+0] = (v.x-gm)*ginv*w4.x + b4.x;
                            hs[pp][d4+1] = (v.y-gm)*ginv*w4.y + b4.y;
                            hs[pp][d4+2] = (v.z-gm)*ginv*w4.z + b4.z;
                            hs[pp][d4+3] = (v.w-gm)*ginv*w4.w + b4.w;
                        }
                    }
                    __syncthreads();
                    {
                        int pp = t >> 3, d4 = (t & 7)*4;
                        if (pp < np) {
                            int n = base + pp;
                            float4 a0 = *(const float4*)&aggWs[d4];
                            float acc0 = a0.x, acc1 = a0.y, acc2 = a0.z, acc3 = a0.w;
                            #pragma unroll
                            for (int k = 0; k < DD; k++) {
                                float hv = hs[pp][k];
                                float4 w = *(const float4*)&sW[k][d4];
                                acc0 += hv*w.x; acc1 += hv*w.y; acc2 += hv*w.z; acc3 += hv*w.w;
                            }
                            float4 o;
                            o.x = tanh_fast(acc0); o.y = tanh_fast(acc1);
                            o.z = tanh_fast(acc2); o.w = tanh_fast(acc3);
                            *(float4*)&p.tbuf[(size_t)n*DD + d4] = o;
                            s1 += (o.x + o.y) + (o.z + o.w);
                            s2 += (o.x*o.x + o.y*o.y) + (o.z*o.z + o.w*o.w);
                        }
                    }
                }
            }
            // block-reduce stats, one atomic per block
            #pragma unroll
            for (int o = 32; o > 0; o >>= 1) { s1 += __shfl_down(s1, o); s2 += __shfl_down(s2, o); }
            __syncthreads();
            int wid = t >> 6;
            if ((t & 63) == 0) { rs1[wid] = s1; rs2[wid] = s2; }
            __syncthreads();
            if (t == 0) {
                float a1 = 0.f, a2 = 0.f;
                #pragma unroll
                for (int q = 0; q < 8; q++) { a1 += rs1[q]; a2 += rs2[q]; }
                atomicAdd(&p.stats[2*L+0], a1);
                atomicAdd(&p.stats[2*L+1], a2);
            }
        }
        grid.sync();
    }

    // ================= readout =================
    {
        float (*red2)[DD] = (float(*)[DD])lds;   // 16x32
        float* sv = lds + 16*DD;
        for (int g = bid; g < NG; g += nb) {
            __syncthreads();
            int d = t & 31, pl = t >> 5;         // 16 point-lanes x 32 dims
            int s0 = p.offs[g], e0 = p.offs[g+1];
            float acc = 0.f;
            for (int n = s0 + pl; n < e0; n += 16) acc += p.tbuf[(size_t)n*DD + d];
            red2[pl][d] = acc;
            __syncthreads();
            if (t < DD) {
                float r = 0.f;
                #pragma unroll
                for (int q = 0; q < 16; q++) r += red2[q][t];
                const float invM = 1.f/((float)NPTS*DD);
                float m = p.stats[16]*invM;
                float var = p.stats[17]*invM - m*m;
                float inv = 1.f/(sqrtf(fmaxf(var, 0.f)) + EPSV);
                float cntf = (float)(e0 - s0);
                float mean = r / fmaxf(cntf, 1.f);
                sv[t] = (e0 > s0) ? (mean - m)*inv*p.gln_w[2*DD+t] + p.gln_b[2*DD+t] : 0.f;
            }
            __syncthreads();
            for (int jj = 0; jj < 3; jj++) {
                float yv = 0.f;
                if (t < DD) {
                    float y = p.bp[jj*DD + t];
                    #pragma unroll
                    for (int i = 0; i < DD; i++) y += sv[i] * p.Wp[jj*DD*DD + i*DD + t];
                    float sum = y;
                    #pragma unroll
                    for (int o = 1; o < 32; o <<= 1) sum += __shfl_xor(sum, o);
                    float m = sum * (1.f/DD);
                    float c = y - m;
                    float sq = c*c;
                    #pragma unroll
                    for (int o = 1; o < 32; o <<= 1) sq += __shfl_xor(sq, o);
                    float var = sq * (1.f/DD);
                    yv = tanh_fast(c / sqrtf(var + EPSV) * p.lnp_w[jj*DD+t] + p.lnp_b[jj*DD+t]);
                }
                __syncthreads();
                if (t < DD) sv[t] = yv;
                __syncthreads();
            }
            if (t < DD) {
                float pr = sv[t] * p.Wpo[t];
                #pragma unroll
                for (int o = 1; o < 32; o <<= 1) pr += __shfl_xor(pr, o);
                if (t == 0) p.out[g] = pr + p.bpo[0];
            }
        }
    }
}

// ==================================================================
// Fallback: round-3 split kernels (proven, absmax 0)
// ==================================================================
__global__ __launch_bounds__(256) void k_init(const int* __restrict__ batch,
                                              int* __restrict__ offs, float* __restrict__ stats) {
    int t = threadIdx.x;
    if (t <= NG) {
        int lo = 0, hi = NPTS;
        while (lo < hi) { int mid = (lo+hi)>>1; if (batch[mid] < t) lo = mid+1; else hi = mid; }
        offs[t] = lo;
    }
    if (t < 32) stats[t] = 0.f;
}

__global__ __launch_bounds__(256) void k_fold(const float* __restrict__ W_in, const float* __restrict__ b_in,
                                              const float* __restrict__ W_out, const float* __restrict__ b_out,
                                              float* __restrict__ Weff, float* __restrict__ beff) {
    int j = blockIdx.x, t = threadIdx.x;
    const float* W0 = W_out + (size_t)j*HINC*DD;
    const float* W1 = W0 + DD*DD;
    const float* Wi = W_in + (size_t)j*DD*FF;
    for (int e = t; e < DD*DD; e += 256) {
        int i = e >> 5, d = e & 31;
        float s = W0[e];
        for (int f = 0; f < FF; f++) s += Wi[i*FF+f] * W1[f*DD+d];
        Weff[j*DD*DD + e] = s;
    }
    if (t < DD) {
        float s = b_out[j*DD + t];
        for (int f = 0; f < FF; f++) s += b_in[j*FF+f] * W1[f*DD+t];
        beff[j*DD + t] = s;
    }
}

__global__ __launch_bounds__(256) void k_embed(const float* __restrict__ x, const float* __restrict__ Wi,
                                               const float* __restrict__ bi, const float* __restrict__ lw,
                                               const float* __restrict__ lb, float* __restrict__ h) {
    int n = blockIdx.x*256 + threadIdx.x;
    if (n >= NPTS) return;
    float x0 = x[n*3], x1 = x[n*3+1], x2 = x[n*3+2];
    float v[DD]; float m = 0.f;
    #pragma unroll
    for (int d = 0; d < DD; d++) {
        float tv = x0*Wi[d] + x1*Wi[DD+d] + x2*Wi[2*DD+d] + bi[d];
        v[d] = tv; m += tv;
    }
    m *= (1.f/DD);
    float var = 0.f;
    #pragma unroll
    for (int d = 0; d < DD; d++) { float c = v[d]-m; var += c*c; }
    var *= (1.f/DD);
    float inv = 1.f/sqrtf(var + EPSV);
    #pragma unroll
    for (int d = 0; d < DD; d++) h[(size_t)n*DD + d] = tanh_fast((v[d]-m)*inv*lw[d] + lb[d]);
}

__global__ __launch_bounds__(512) void k_A(const float* __restrict__ inb, const float* __restrict__ stats,
                                           const float* __restrict__ gw, const float* __restrict__ gb,
                                           const float* __restrict__ Win, const float* __restrict__ bin,
                                           const float* __restrict__ Wsc, const float* __restrict__ bsc,
                                           const int* __restrict__ offs,
                                           float* __restrict__ psum, float* __restrict__ pmax) {
    int g = blockIdx.x / SMAX;
    int s = blockIdx.x - g*SMAX;
    int gs = offs[g], ge = offs[g+1];
    int cnt = ge - gs;
    int start = s*CH;
    if (start >= cnt) return;
    int end = (s == SMAX-1) ? cnt : min(cnt, start + CH);
    __shared__ float hs[CH][36];
    __shared__ float sxp[CH][68];
    __shared__ float sattn[CH][9];
    __shared__ float sWin[DD*FF];
    __shared__ float sScT[AA*FF];
    int t = threadIdx.x;
    for (int k = t; k < DD*FF; k += 512) sWin[k] = Win[k];
    if (t < AA*FF) { int a = t >> 6, f = t & 63; sScT[t] = Wsc[f*AA + a]; }
    float m = 0.f, inv = 1.f;
    if (stats) {
        const float invM = 1.f/((float)NPTS*DD);
        m = stats[0]*invM;
        float var = stats[1]*invM - m*m;
        inv = 1.f/(sqrtf(fmaxf(var, 0.f)) + EPSV);
    }
    int pt = t >> 3, fo = (t & 7)*8, al = t & 7;
    float bscv = bsc[al];
    float4 bi0 = *(const float4*)&bin[fo];
    float4 bi1 = *(const float4*)&bin[fo+4];
    int ca = t >> 6, cf = t & 63;
    float csum = 0.f, cmax = -INFINITY;
    for (int base = start; base < end; base += CH) {
        int np = min(CH, end - base);
        __syncthreads();
        {
            int pp = t >> 3, d4 = (t & 7)*4;
            if (pp < np) {
                int n = gs + base + pp;
                float4 v = *(const float4*)&inb[(size_t)n*DD + d4];
                float4 w4 = make_float4(1,1,1,1), b4 = make_float4(0,0,0,0);
                if (gw) { w4 = *(const float4*)&gw[d4]; b4 = *(const float4*)&gb[d4]; }
                hs[pp][d4+0] = (v.x-m)*inv*w4.x + b4.x;
                hs[pp][d4+1] = (v.y-m)*inv*w4.y + b4.y;
                hs[pp][d4+2] = (v.z-m)*inv*w4.z + b4.z;
                hs[pp][d4+3] = (v.w-m)*inv*w4.w + b4.w;
            }
        }
        __syncthreads();
        if (pt < np) {
            float xr[8] = {bi0.x,bi0.y,bi0.z,bi0.w,bi1.x,bi1.y,bi1.z,bi1.w};
            #pragma unroll
            for (int k = 0; k < DD; k++) {
                float hv = hs[pt][k];
                float4 wa = *(const float4*)&sWin[k*FF + fo];
                float4 wb = *(const float4*)&sWin[k*FF + fo + 4];
                xr[0] += hv*wa.x; xr[1] += hv*wa.y; xr[2] += hv*wa.z; xr[3] += hv*wa.w;
                xr[4] += hv*wb.x; xr[5] += hv*wb.y; xr[6] += hv*wb.z; xr[7] += hv*wb.w;
            }
            float pa[8];
            #pragma unroll
            for (int a = 0; a < 8; a++) {
                float4 wa = *(const float4*)&sScT[a*FF + fo];
                float4 wb = *(const float4*)&sScT[a*FF + fo + 4];
                pa[a] = xr[0]*wa.x + xr[1]*wa.y + xr[2]*wa.z + xr[3]*wa.w
                      + xr[4]*wb.x + xr[5]*wb.y + xr[6]*wb.z + xr[7]*wb.w;
            }
            #pragma unroll
            for (int msk = 1; msk < 8; msk <<= 1) {
                #pragma unroll
                for (int a = 0; a < 8; a++) pa[a] += __shfl_xor(pa[a], msk);
            }
            sattn[pt][al] = __expf(-fabsf(pa[al] + bscv));
            *(float4*)&sxp[pt][fo]   = make_float4(xr[0],xr[1],xr[2],xr[3]);
            *(float4*)&sxp[pt][fo+4] = make_float4(xr[4],xr[5],xr[6],xr[7]);
        }
        __syncthreads();
        for (int pp = 0; pp < np; pp++) {
            float w = sattn[pp][ca] * sxp[pp][cf];
            csum += w; cmax = fmaxf(cmax, w);
        }
    }
    size_t pb = ((size_t)g*SMAX + s)*512;
    psum[pb + t] = csum; pmax[pb + t] = cmax;
}

__global__ __launch_bounds__(512) void k_B(const float* __restrict__ psum, const float* __restrict__ pmax,
                                           const int* __restrict__ offs, const float* __restrict__ Wagg,
                                           const float* __restrict__ beff, float* __restrict__ aggW) {
    int g = blockIdx.x, t = threadIdx.x;
    int cnt = offs[g+1] - offs[g];
    int nch = min((cnt + CH - 1)/CH, SMAX);
    float sum = 0.f, mx = -INFINITY;
    size_t pb = (size_t)g*SMAX*512;
    for (int s = 0; s < nch; s++) {
        sum += psum[pb + s*512 + t];
        mx = fmaxf(mx, pmax[pb + s*512 + t]);
    }
    float mean = sum / fmaxf((float)cnt, 1.f);
    if (cnt <= 0) { mean = 0.f; mx = 0.f; }
    __shared__ float agg[2*FF*AA];
    int a = t >> 6, f = t & 63;
    agg[a*2*FF + f]      = mean;
    agg[a*2*FF + FF + f] = mx;
    __syncthreads();
    int d = t & 31, grp = t >> 5;
    float acc = 0.f;
    #pragma unroll
    for (int k2 = 0; k2 < 64; k2++) {
        int k = grp*64 + k2;
        acc += agg[k] * Wagg[k*DD + d];
    }
    __shared__ float red[16][DD];
    red[grp][d] = acc;
    __syncthreads();
    if (t < DD) {
        float r = 0.f;
        #pragma unroll
        for (int q = 0; q < 16; q++) r += red[q][t];
        aggW[g*DD + t] = r + beff[t];
    }
}

__global__ __launch_bounds__(512) void k_C(const float* inb, const float* __restrict__ stats,
                                           const float* __restrict__ gw, const float* __restrict__ gb,
                                           const float* __restrict__ aggW, const int* __restrict__ batch,
                                           const float* __restrict__ Weff, float* tbuf,
                                           float* __restrict__ statsO) {
    __shared__ float hs[64][36];
    __shared__ float sW[DD][36];
    int t = threadIdx.x;
    for (int k = t; k < DD*DD; k += 512) sW[k>>5][k&31] = Weff[k];
    float m = 0.f, inv = 1.f;
    if (stats) {
        const float invM = 1.f/((float)NPTS*DD);
        m = stats[0]*invM;
        float var = stats[1]*invM - m*m;
        inv = 1.f/(sqrtf(fmaxf(var, 0.f)) + EPSV);
    }
    int b0 = blockIdx.x*64;
    {
        int pp = t >> 3, d4 = (t & 7)*4;
        int n = b0 + pp;
        if (n < NPTS) {
            float4 v = *(const float4*)&inb[(size_t)n*DD + d4];
            float4 w4 = make_float4(1,1,1,1), b4 = make_float4(0,0,0,0);
            if (gw) { w4 = *(const float4*)&gw[d4]; b4 = *(const float4*)&gb[d4]; }
            hs[pp][d4+0] = (v.x-m)*inv*w4.x + b4.x;
            hs[pp][d4+1] = (v.y-m)*inv*w4.y + b4.y;
            hs[pp][d4+2] = (v.z-m)*inv*w4.z + b4.z;
            hs[pp][d4+3] = (v.w-m)*inv*w4.w + b4.w;
        }
    }
    __syncthreads();
    int pt = t >> 3, q4 = (t & 7)*4;
    int n = b0 + pt;
    float s1 = 0.f, s2 = 0.f;
    if (n < NPTS) {
        int g = batch[n];
        float4 a0 = *(const float4*)&aggW[g*DD + q4];
        float acc0 = a0.x, acc1 = a0.y, acc2 = a0.z, acc3 = a0.w;
        #pragma unroll
        for (int k = 0; k < DD; k++) {
            float hv = hs[pt][k];
            float4 w = *(const float4*)&sW[k][q4];
            acc0 += hv*w.x; acc1 += hv*w.y; acc2 += hv*w.z; acc3 += hv*w.w;
        }
        float4 o;
        o.x = tanh_fast(acc0); o.y = tanh_fast(acc1);
        o.z = tanh_fast(acc2); o.w = tanh_fast(acc3);
        *(float4*)&tbuf[(size_t)n*DD + q4] = o;
        s1 = (o.x + o.y) + (o.z + o.w);
        s2 = (o.x*o.x + o.y*o.y) + (o.z*o.z + o.w*o.w);
    }
    #pragma unroll
    for (int o = 32; o > 0; o >>= 1) { s1 += __shfl_down(s1, o); s2 += __shfl_down(s2, o); }
    __shared__ float rs1[8], rs2[8];
    int wid = t >> 6;
    if ((t & 63) == 0) { rs1[wid] = s1; rs2[wid] = s2; }
    __syncthreads();
    if (t == 0) {
        float a1 = 0.f, a2 = 0.f;
        #pragma unroll
        for (int q = 0; q < 8; q++) { a1 += rs1[q]; a2 += rs2[q]; }
        atomicAdd(&statsO[0], a1);
        atomicAdd(&statsO[1], a2);
    }
}

__global__ __launch_bounds__(256) void k_read(const float* __restrict__ tbuf, const float* __restrict__ stats,
                                              const float* __restrict__ gw, const float* __restrict__ gb,
                                              const int* __restrict__ offs, const float* __restrict__ Wp,
                                              const float* __restrict__ bp, const float* __restrict__ lnw,
                                              const float* __restrict__ lnb, const float* __restrict__ Wpo,
                                              const float* __restrict__ bpo, float* __restrict__ out) {
    int g = blockIdx.x;
    int t = threadIdx.x;
    int d = t & 31, pl = t >> 5;
    int s0 = offs[g], e0 = offs[g+1];
    float acc = 0.f;
    for (int n = s0 + pl; n < e0; n += 8) acc += tbuf[(size_t)n*DD + d];
    __shared__ float red[8][DD];
    red[pl][d] = acc;
    __syncthreads();
    __shared__ float sv[DD];
    if (t < DD) {
        float r = 0.f;
        #pragma unroll
        for (int q = 0; q < 8; q++) r += red[q][t];
        const float invM = 1.f/((float)NPTS*DD);
        float m = stats[0]*invM;
        float var = stats[1]*invM - m*m;
        float inv = 1.f/(sqrtf(fmaxf(var, 0.f)) + EPSV);
        float cnt = (float)(e0 - s0);
        float mean = r / fmaxf(cnt, 1.f);
        sv[t] = (e0 > s0) ? (mean - m)*inv*gw[t] + gb[t] : 0.f;
    }
    __syncthreads();
    for (int j = 0; j < 3; j++) {
        float yv = 0.f;
        if (t < DD) {
            float y = bp[j*DD + t];
            #pragma unroll
            for (int i = 0; i < DD; i++) y += sv[i] * Wp[j*DD*DD + i*DD + t];
            float sum = y;
            #pragma unroll
            for (int o = 1; o < 32; o <<= 1) sum += __shfl_xor(sum, o);
            float m = sum * (1.f/DD);
            float c = y - m;
            float sq = c*c;
            #pragma unroll
            for (int o = 1; o < 32; o <<= 1) sq += __shfl_xor(sq, o);
            float var = sq * (1.f/DD);
            yv = tanh_fast(c / sqrtf(var + EPSV) * lnw[j*DD+t] + lnb[j*DD+t]);
        }
        __syncthreads();
        if (t < DD) sv[t] = yv;
        __syncthreads();
    }
    if (t < DD) {
        float p = sv[t] * Wpo[t];
        #pragma unroll
        for (int o = 1; o < 32; o <<= 1) p += __shfl_xor(p, o);
        if (t == 0) out[g] = p + bpo[0];
    }
}

extern "C" void kernel_launch(void* const* d_in, const int* in_sizes, int n_in,
                              void* d_out, int out_size, void* d_ws, size_t ws_size,
                              hipStream_t stream) {
    KP hp;
    hp.x     = (const float*)d_in[0];
    hp.batch = (const int*)  d_in[1];
    hp.Wi    = (const float*)d_in[2];
    hp.bi    = (const float*)d_in[3];
    hp.lni_w = (const float*)d_in[4];
    hp.lni_b = (const float*)d_in[5];
    hp.W_in  = (const float*)d_in[6];
    hp.b_in  = (const float*)d_in[7];
    hp.W_sc  = (const float*)d_in[8];
    hp.b_sc  = (const float*)d_in[9];
    hp.W_out = (const float*)d_in[10];
    hp.b_out = (const float*)d_in[11];
    hp.gln_w = (const float*)d_in[12];
    hp.gln_b = (const float*)d_in[13];
    hp.Wp    = (const float*)d_in[14];
    hp.bp    = (const float*)d_in[15];
    hp.lnp_w = (const float*)d_in[16];
    hp.lnp_b = (const float*)d_in[17];
    hp.Wpo   = (const float*)d_in[18];
    hp.bpo   = (const float*)d_in[19];
    hp.out   = (float*)d_out;

    float* ws = (float*)d_ws;
    hp.h     = ws;                                      // NPTS*32
    hp.tbuf  = hp.h    + (size_t)NPTS*DD;               // NPTS*32
    hp.aggW  = hp.tbuf + (size_t)NPTS*DD;               // NG*32 (fallback only)
    hp.stats = hp.aggW + NG*DD;                         // 32
    hp.Weff  = hp.stats + 32;                           // 3*1024
    hp.beff  = hp.Weff + 3*DD*DD;                       // 96
    hp.psum  = hp.beff + 3*DD;                          // NG*SMAX*512
    hp.pmax  = hp.psum + (size_t)NG*SMAX*512;           // NG*SMAX*512
    hp.offs  = (int*)(hp.pmax + (size_t)NG*SMAX*512);   // NG+1

    // --- try cooperative mega-kernel at the grid size the runtime permits ---
    int occ = 0;
    hipError_t oe = hipOccupancyMaxActiveBlocksPerMultiprocessor(&occ, mega, NT, 0);
    int nb = (oe == hipSuccess && occ > 0) ? occ * 256 : 0;
    if (nb > 256) nb = 256;
    hipError_t le = hipErrorUnknown;
    if (nb >= 16) {
        void* kargs[] = { (void*)&hp };
        le = hipLaunchCooperativeKernel(mega, dim3(nb), dim3(NT), kargs, 0, stream);
    }
    if (le == hipSuccess) return;
    (void)hipGetLastError();   // clear sticky error from the failed attempt

    // --- fallback: proven split-kernel path (round-3) ---
    k_init<<<1, 256, 0, stream>>>(hp.batch, hp.offs, hp.stats);
    k_fold<<<3, 256, 0, stream>>>(hp.W_in, hp.b_in, hp.W_out, hp.b_out, hp.Weff, hp.beff);
    k_embed<<<(NPTS+255)/256, 256, 0, stream>>>(hp.x, hp.Wi, hp.bi, hp.lni_w, hp.lni_b, hp.h);
    for (int it = 0; it < 3; it++) {
        for (int j = 0; j < 3; j++) {
            int L = it*3 + j;
            const float* inb = L ? hp.tbuf : hp.h;
            const float* st  = L ? hp.stats + 2*(L-1) : nullptr;
            int pj = (L + 2) % 3;
            const float* pgw = L ? hp.gln_w + pj*DD : nullptr;
            const float* pgb = L ? hp.gln_b + pj*DD : nullptr;
            k_A<<<NG*SMAX, 512, 0, stream>>>(
                inb, st, pgw, pgb,
                hp.W_in + (size_t)j*DD*FF, hp.b_in + j*FF,
                hp.W_sc + (size_t)j*FF*AA, hp.b_sc + j*AA,
                hp.offs, hp.psum, hp.pmax);
            k_B<<<NG, 512, 0, stream>>>(
                hp.psum, hp.pmax, hp.offs,
                hp.W_out + (size_t)j*HINC*DD + (size_t)96*DD, hp.beff + j*DD, hp.aggW);
            k_C<<<(NPTS+63)/64, 512, 0, stream>>>(
                inb, st, pgw, pgb, hp.aggW, hp.batch,
                hp.Weff + (size_t)j*DD*DD, hp.tbuf, hp.stats + 2*L);
        }
    }
    k_read<<<NG, 256, 0, stream>>>(hp.tbuf, hp.stats + 16, hp.gln_w + 2*DD, hp.gln_b + 2*DD,
                                   hp.offs, hp.Wp, hp.bp, hp.lnp_w, hp.lnp_b, hp.Wpo, hp.bpo, hp.out);
}